// Round 7
// baseline (159.312 us; speedup 1.0000x reference)
//
#include <hip/hip_runtime.h>

// GCN 2-layer encoder for MI355X (gfx950) — round 7.
// r6 post-mortem: fused gather+gemm2 REGRESSED (57us vs 25+12 split): 50KB LDS
// -> 14% occupancy starved the latency-bound gather phase. Reverted to split.
// r7: (a) gather1 emits relu(agg)+b1 as bf16 (halves agg round-trip);
// (b) gemm2 reads bf16; (c) fill+count process 4 consecutive edges/thread via
// int4 loads (4 independent atomic->store chains, 4x edge-read coalescing),
// fill gets 1024 blocks.
//
// Pipeline (8 dispatches):
//   k_init -> k_count -> k_scan1 -> k_scan3 -> k_gemm_fill(gemm1 || fill)
//   -> k_gather_relu(h1b -> aggb bf16) -> k_gemm2(aggb -> h2b)
//   -> k_gather<64>(h2b -> out f32)

constexpr int IN_CH  = 128;
constexpr int HID    = 128;
constexpr int OUT_CH = 64;
constexpr int SCAN_CHUNK = 4096;   // 256 threads x 16 elements

__device__ __forceinline__ unsigned short f2bf_rne(float f) {
    unsigned int u = __float_as_uint(f);
    u += 0x7FFFu + ((u >> 16) & 1u);
    return (unsigned short)(u >> 16);
}
__device__ __forceinline__ float bf2f(unsigned short h) {
    return __uint_as_float((unsigned int)h << 16);
}

// Wave-level dtype probe: odd dwords of the first 64 int64 lanes are hi-words
// (== 0 for node ids < 2^31). For int32 data they are random node ids.
__device__ __forceinline__ bool probe_is64(const int* __restrict__ ei) {
    const int v = ei[2 * (threadIdx.x & 63) + 1];
    return __ballot(v != 0) == 0ull;
}

// Load 4 consecutive indices from a (possibly int64) index array half.
// base = element offset of the half (0 for src, E for dst).
__device__ __forceinline__ void load_idx4(const int* __restrict__ ei, bool is64,
                                          long long base, int e0, int n,
                                          bool al64, bool al32, int* out) {
    if (is64) {
        if (n == 4 && al64) {
            const int4 a = *reinterpret_cast<const int4*>(ei + 2 * (base + e0));
            const int4 b = *reinterpret_cast<const int4*>(ei + 2 * (base + e0) + 4);
            out[0] = a.x; out[1] = a.z; out[2] = b.x; out[3] = b.z;
        } else {
            for (int j = 0; j < n; ++j) out[j] = ei[2 * (base + e0 + j)];
        }
    } else {
        if (n == 4 && al32) {
            const int4 a = *reinterpret_cast<const int4*>(ei + base + e0);
            out[0] = a.x; out[1] = a.y; out[2] = a.z; out[3] = a.w;
        } else {
            for (int j = 0; j < n; ++j) out[j] = ei[base + e0 + j];
        }
    }
}

__global__ void k_init(int* __restrict__ indeg, int N) {
    const int i = blockIdx.x * blockDim.x + threadIdx.x;
    const int n4 = N / 4;
    for (int j = i; j < n4; j += gridDim.x * blockDim.x)
        reinterpret_cast<int4*>(indeg)[j] = make_int4(0, 0, 0, 0);
    const int tail = n4 * 4 + i;
    if (tail < N) indeg[tail] = 0;
}

__global__ void k_count(const int* __restrict__ ei, int* __restrict__ indeg, int E) {
    const bool is64 = probe_is64(ei);
    const bool al64 = (E % 2) == 0;   // int4 alignment for 2*(E+e0)
    const bool al32 = (E % 4) == 0;   // int4 alignment for E+e0
    const int idx    = blockIdx.x * blockDim.x + threadIdx.x;
    const int stride = gridDim.x * blockDim.x;
    for (int e0 = idx * 4; e0 < E; e0 += stride * 4) {
        const int n = min(4, E - e0);
        int d[4];
        load_idx4(ei, is64, (long long)E, e0, n, al64, al32, d);
        for (int j = 0; j < n; ++j) atomicAdd(&indeg[d[j]], 1);
    }
}

// Local exclusive scan of indeg over SCAN_CHUNK blocks; emits dinv = rsqrt(indeg+1)
// (+1 = self loop) and partials[b] = block total.
__global__ __launch_bounds__(256) void k_scan1(const int* __restrict__ indeg,
                                               int* __restrict__ row_ptr,
                                               float* __restrict__ dinv,
                                               int* __restrict__ partials, int N) {
    const int t    = threadIdx.x;
    const int base = blockIdx.x * SCAN_CHUNK + t * 16;
    int v[16];
    if (base + 15 < N) {
        const int4* p = reinterpret_cast<const int4*>(indeg + base);
#pragma unroll
        for (int q = 0; q < 4; ++q) {
            const int4 a = p[q];
            v[q * 4 + 0] = a.x; v[q * 4 + 1] = a.y;
            v[q * 4 + 2] = a.z; v[q * 4 + 3] = a.w;
        }
    } else {
#pragma unroll
        for (int j = 0; j < 16; ++j)
            v[j] = (base + j < N) ? indeg[base + j] : 0;
    }
#pragma unroll
    for (int j = 0; j < 16; ++j)
        if (base + j < N) dinv[base + j] = rsqrtf((float)(v[j] + 1));

    int sum = 0;
#pragma unroll
    for (int j = 0; j < 16; ++j) { const int tv = v[j]; v[j] = sum; sum += tv; }

    int incl = sum;
#pragma unroll
    for (int off = 1; off < 64; off <<= 1) {
        int tt = __shfl_up(incl, off, 64);
        if ((t & 63) >= off) incl += tt;
    }
    __shared__ int wsum[4];
    if ((t & 63) == 63) wsum[t >> 6] = incl;
    __syncthreads();
    int woff = 0;
#pragma unroll
    for (int w = 0; w < 4; ++w) woff += (w < (t >> 6)) ? wsum[w] : 0;
    const int texcl = woff + incl - sum;

#pragma unroll
    for (int j = 0; j < 16; ++j)
        if (base + j < N) row_ptr[base + j] = texcl + v[j];
    if (t == 255) partials[blockIdx.x] = woff + incl;
}

// Apply block offsets; write cursor; last block writes row_ptr[N].
__global__ __launch_bounds__(256) void k_scan3(const int* __restrict__ partials,
                                               int* __restrict__ row_ptr,
                                               int* __restrict__ cursor,
                                               int N, int nblk) {
    int off = 0;
    for (int w = 0; w < (int)blockIdx.x; ++w) off += partials[w];

    const int base = blockIdx.x * SCAN_CHUNK + threadIdx.x * 16;
    if (base + 15 < N) {
        int4* rp = reinterpret_cast<int4*>(row_ptr + base);
        int4* cp = reinterpret_cast<int4*>(cursor + base);
#pragma unroll
        for (int q = 0; q < 4; ++q) {
            int4 a = rp[q];
            a.x += off; a.y += off; a.z += off; a.w += off;
            rp[q] = a; cp[q] = a;
        }
    } else {
#pragma unroll
        for (int j = 0; j < 16; ++j) {
            const int i = base + j;
            if (i < N) { const int r = row_ptr[i] + off; row_ptr[i] = r; cursor[i] = r; }
        }
    }
    if ((int)blockIdx.x == nblk - 1 && threadIdx.x == 255)
        row_ptr[N] = off + partials[nblk - 1];
}

// GEMM body: Y[M x NC](bf16) = X[M x 128](f32, opt ReLU) @ W[128 x NC](f32).
template <int NC, bool RELU>
__device__ __forceinline__ void gemm_body(const float* __restrict__ X,
                                          const float* __restrict__ W,
                                          unsigned short* __restrict__ Y,
                                          int M, int blk) {
    constexpr int COL4   = NC / 4;
    constexpr int ROWT   = 256 / COL4;
    constexpr int TILE_R = 8 * ROWT;
    constexpr int XS_STRIDE = 36;

    __shared__ __align__(16) float ws[32 * NC];
    __shared__ __align__(16) float xs[TILE_R * XS_STRIDE];

    const int tid  = threadIdx.x;
    const int row0 = blk * TILE_R;
    const int tx   = tid % COL4;
    const int ty   = tid / COL4;

    float4 acc[8];
#pragma unroll
    for (int j = 0; j < 8; ++j) acc[j] = make_float4(0.f, 0.f, 0.f, 0.f);

    for (int k0 = 0; k0 < 128; k0 += 32) {
        __syncthreads();
        {
            constexpr int NF4 = 32 * NC / 4;
#pragma unroll
            for (int i = tid; i < NF4; i += 256)
                reinterpret_cast<float4*>(ws)[i] =
                    reinterpret_cast<const float4*>(W + (size_t)k0 * NC)[i];
        }
        {
            const int c  = tid & 7;
            const int rb = tid >> 3;
#pragma unroll
            for (int r = rb; r < TILE_R; r += 32) {
                const int gr = row0 + r;
                float4 v = make_float4(0.f, 0.f, 0.f, 0.f);
                if (gr < M)
                    v = *reinterpret_cast<const float4*>(X + (size_t)gr * 128 + k0 + c * 4);
                if (RELU) {
                    v.x = fmaxf(v.x, 0.f); v.y = fmaxf(v.y, 0.f);
                    v.z = fmaxf(v.z, 0.f); v.w = fmaxf(v.w, 0.f);
                }
                *reinterpret_cast<float4*>(&xs[r * XS_STRIDE + c * 4]) = v;
            }
        }
        __syncthreads();

#pragma unroll
        for (int kk = 0; kk < 32; kk += 4) {
            float4 wv[4];
#pragma unroll
            for (int i = 0; i < 4; ++i)
                wv[i] = *reinterpret_cast<const float4*>(&ws[(kk + i) * NC + tx * 4]);
#pragma unroll
            for (int j = 0; j < 8; ++j) {
                const float4 xv =
                    *reinterpret_cast<const float4*>(&xs[(ty + ROWT * j) * XS_STRIDE + kk]);
                acc[j].x = fmaf(xv.x, wv[0].x, acc[j].x);
                acc[j].y = fmaf(xv.x, wv[0].y, acc[j].y);
                acc[j].z = fmaf(xv.x, wv[0].z, acc[j].z);
                acc[j].w = fmaf(xv.x, wv[0].w, acc[j].w);
                acc[j].x = fmaf(xv.y, wv[1].x, acc[j].x);
                acc[j].y = fmaf(xv.y, wv[1].y, acc[j].y);
                acc[j].z = fmaf(xv.y, wv[1].z, acc[j].z);
                acc[j].w = fmaf(xv.y, wv[1].w, acc[j].w);
                acc[j].x = fmaf(xv.z, wv[2].x, acc[j].x);
                acc[j].y = fmaf(xv.z, wv[2].y, acc[j].y);
                acc[j].z = fmaf(xv.z, wv[2].z, acc[j].z);
                acc[j].w = fmaf(xv.z, wv[2].w, acc[j].w);
                acc[j].x = fmaf(xv.w, wv[3].x, acc[j].x);
                acc[j].y = fmaf(xv.w, wv[3].y, acc[j].y);
                acc[j].z = fmaf(xv.w, wv[3].z, acc[j].z);
                acc[j].w = fmaf(xv.w, wv[3].w, acc[j].w);
            }
        }
    }

#pragma unroll
    for (int j = 0; j < 8; ++j) {
        const int gr = row0 + ty + ROWT * j;
        if (gr < M) {
            ushort4 o;
            o.x = f2bf_rne(acc[j].x);
            o.y = f2bf_rne(acc[j].y);
            o.z = f2bf_rne(acc[j].z);
            o.w = f2bf_rne(acc[j].w);
            *reinterpret_cast<ushort4*>(Y + (size_t)gr * NC + tx * 4) = o;
        }
    }
}

// Dual-role dispatch: blocks [0, gemmBlocks) run gemm1; the rest run the CSR
// fill, 4 consecutive edges per thread (int4 loads, 4 chains in flight).
__global__ __launch_bounds__(256) void k_gemm_fill(
    const float* __restrict__ X, const float* __restrict__ W,
    unsigned short* __restrict__ Y, int M, int gemmBlocks,
    const int* __restrict__ ei, const float* __restrict__ dinv,
    int* __restrict__ cursor, int2* __restrict__ csr, int E) {
    if ((int)blockIdx.x < gemmBlocks) {
        gemm_body<HID, false>(X, W, Y, M, blockIdx.x);
    } else {
        const bool is64 = probe_is64(ei);
        const bool al64 = (E % 2) == 0;
        const bool al32 = (E % 4) == 0;
        const int nthr = (gridDim.x - gemmBlocks) * 256;
        const int idx  = (blockIdx.x - gemmBlocks) * 256 + threadIdx.x;
        for (int e0 = idx * 4; e0 < E; e0 += nthr * 4) {
            const int n = min(4, E - e0);
            int s[4], d[4];
            load_idx4(ei, is64, 0,            e0, n, true, true, s);
            load_idx4(ei, is64, (long long)E, e0, n, al64, al32, d);
            float w[4];
            for (int j = 0; j < n; ++j) w[j] = dinv[s[j]];
            int pos[4];
            for (int j = 0; j < n; ++j) pos[j] = atomicAdd(&cursor[d[j]], 1);
            for (int j = 0; j < n; ++j) {
                const unsigned long long rec =
                    (unsigned long long)(unsigned int)s[j] |
                    ((unsigned long long)__float_as_uint(w[j]) << 32);
                __builtin_nontemporal_store(
                    rec, reinterpret_cast<unsigned long long*>(csr) + pos[j]);
            }
        }
    }
}

// aggb[n](bf16) = relu(b1 + h[n]*dinv[n]^2 + sum_e h[rec.src]*rec.w*dinv[n])
// 32 lanes/node, 4 channels each; bf16 in, f32 accumulate, bf16 out.
__global__ __launch_bounds__(256) void k_gather_relu(
    const unsigned short* __restrict__ h, const int* __restrict__ row_ptr,
    const int2* __restrict__ csr, const float* __restrict__ dinv,
    const float* __restrict__ b, unsigned short* __restrict__ aggb, int N) {
    constexpr int LPN = HID / 4;   // 32
    const int tid  = blockIdx.x * blockDim.x + threadIdx.x;
    const int node = tid / LPN;
    const int lane = tid % LPN;
    if (node >= N) return;

    const float dn = dinv[node];
    float4 acc = reinterpret_cast<const float4*>(b)[lane];
    {
        const float w = dn * dn;  // self loop
        const ushort4 v = *reinterpret_cast<const ushort4*>(h + (size_t)node * HID + lane * 4);
        acc.x = fmaf(bf2f(v.x), w, acc.x); acc.y = fmaf(bf2f(v.y), w, acc.y);
        acc.z = fmaf(bf2f(v.z), w, acc.z); acc.w = fmaf(bf2f(v.w), w, acc.w);
    }

    const int e1 = row_ptr[node + 1];
    int e = row_ptr[node];
    for (; e + 1 < e1; e += 2) {
        const int2 r0 = csr[e];
        const int2 r1 = csr[e + 1];
        const float w0 = __int_as_float(r0.y) * dn;
        const float w1 = __int_as_float(r1.y) * dn;
        const ushort4 v0 = *reinterpret_cast<const ushort4*>(h + (size_t)r0.x * HID + lane * 4);
        const ushort4 v1 = *reinterpret_cast<const ushort4*>(h + (size_t)r1.x * HID + lane * 4);
        acc.x = fmaf(bf2f(v0.x), w0, acc.x); acc.y = fmaf(bf2f(v0.y), w0, acc.y);
        acc.z = fmaf(bf2f(v0.z), w0, acc.z); acc.w = fmaf(bf2f(v0.w), w0, acc.w);
        acc.x = fmaf(bf2f(v1.x), w1, acc.x); acc.y = fmaf(bf2f(v1.y), w1, acc.y);
        acc.z = fmaf(bf2f(v1.z), w1, acc.z); acc.w = fmaf(bf2f(v1.w), w1, acc.w);
    }
    if (e < e1) {
        const int2 r0 = csr[e];
        const float w0 = __int_as_float(r0.y) * dn;
        const ushort4 v0 = *reinterpret_cast<const ushort4*>(h + (size_t)r0.x * HID + lane * 4);
        acc.x = fmaf(bf2f(v0.x), w0, acc.x); acc.y = fmaf(bf2f(v0.y), w0, acc.y);
        acc.z = fmaf(bf2f(v0.z), w0, acc.z); acc.w = fmaf(bf2f(v0.w), w0, acc.w);
    }

    ushort4 o;
    o.x = f2bf_rne(fmaxf(acc.x, 0.f));
    o.y = f2bf_rne(fmaxf(acc.y, 0.f));
    o.z = f2bf_rne(fmaxf(acc.z, 0.f));
    o.w = f2bf_rne(fmaxf(acc.w, 0.f));
    *reinterpret_cast<ushort4*>(aggb + (size_t)node * HID + lane * 4) = o;
}

// GEMM2: Y[M x 64](bf16) = Xb[M x 128](bf16) @ W[128 x 64](f32).
// Same tiling as gemm_body<64>, bf16 staging converted to f32 in LDS.
__global__ __launch_bounds__(256) void k_gemm2(const unsigned short* __restrict__ Xb,
                                               const float* __restrict__ W,
                                               unsigned short* __restrict__ Y, int M) {
    constexpr int NC     = OUT_CH;
    constexpr int COL4   = NC / 4;       // 16
    constexpr int ROWT   = 256 / COL4;   // 16
    constexpr int TILE_R = 8 * ROWT;     // 128
    constexpr int XS_STRIDE = 36;

    __shared__ __align__(16) float ws[32 * NC];
    __shared__ __align__(16) float xs[TILE_R * XS_STRIDE];

    const int tid  = threadIdx.x;
    const int row0 = blockIdx.x * TILE_R;
    const int tx   = tid % COL4;
    const int ty   = tid / COL4;

    float4 acc[8];
#pragma unroll
    for (int j = 0; j < 8; ++j) acc[j] = make_float4(0.f, 0.f, 0.f, 0.f);

    for (int k0 = 0; k0 < 128; k0 += 32) {
        __syncthreads();
        {
            constexpr int NF4 = 32 * NC / 4;
#pragma unroll
            for (int i = tid; i < NF4; i += 256)
                reinterpret_cast<float4*>(ws)[i] =
                    reinterpret_cast<const float4*>(W + (size_t)k0 * NC)[i];
        }
        {
            const int c  = tid & 7;
            const int rb = tid >> 3;
#pragma unroll
            for (int r = rb; r < TILE_R; r += 32) {
                const int gr = row0 + r;
                float4 v = make_float4(0.f, 0.f, 0.f, 0.f);
                if (gr < M) {
                    const ushort4 u = *reinterpret_cast<const ushort4*>(
                        Xb + (size_t)gr * 128 + k0 + c * 4);
                    v = make_float4(bf2f(u.x), bf2f(u.y), bf2f(u.z), bf2f(u.w));
                }
                *reinterpret_cast<float4*>(&xs[r * XS_STRIDE + c * 4]) = v;
            }
        }
        __syncthreads();

#pragma unroll
        for (int kk = 0; kk < 32; kk += 4) {
            float4 wv[4];
#pragma unroll
            for (int i = 0; i < 4; ++i)
                wv[i] = *reinterpret_cast<const float4*>(&ws[(kk + i) * NC + tx * 4]);
#pragma unroll
            for (int j = 0; j < 8; ++j) {
                const float4 xv =
                    *reinterpret_cast<const float4*>(&xs[(ty + ROWT * j) * XS_STRIDE + kk]);
                acc[j].x = fmaf(xv.x, wv[0].x, acc[j].x);
                acc[j].y = fmaf(xv.x, wv[0].y, acc[j].y);
                acc[j].z = fmaf(xv.x, wv[0].z, acc[j].z);
                acc[j].w = fmaf(xv.x, wv[0].w, acc[j].w);
                acc[j].x = fmaf(xv.y, wv[1].x, acc[j].x);
                acc[j].y = fmaf(xv.y, wv[1].y, acc[j].y);
                acc[j].z = fmaf(xv.y, wv[1].z, acc[j].z);
                acc[j].w = fmaf(xv.y, wv[1].w, acc[j].w);
                acc[j].x = fmaf(xv.z, wv[2].x, acc[j].x);
                acc[j].y = fmaf(xv.z, wv[2].y, acc[j].y);
                acc[j].z = fmaf(xv.z, wv[2].z, acc[j].z);
                acc[j].w = fmaf(xv.z, wv[2].w, acc[j].w);
                acc[j].x = fmaf(xv.w, wv[3].x, acc[j].x);
                acc[j].y = fmaf(xv.w, wv[3].y, acc[j].y);
                acc[j].z = fmaf(xv.w, wv[3].z, acc[j].z);
                acc[j].w = fmaf(xv.w, wv[3].w, acc[j].w);
            }
        }
    }

#pragma unroll
    for (int j = 0; j < 8; ++j) {
        const int gr = row0 + ty + ROWT * j;
        if (gr < M) {
            ushort4 o;
            o.x = f2bf_rne(acc[j].x);
            o.y = f2bf_rne(acc[j].y);
            o.z = f2bf_rne(acc[j].z);
            o.w = f2bf_rne(acc[j].w);
            *reinterpret_cast<ushort4*>(Y + (size_t)gr * NC + tx * 4) = o;
        }
    }
}

// out[n](f32) = b + h[n]*dinv[n]^2 + sum_e h[rec.src]*rec.w*dinv[n]
template <int C>
__global__ __launch_bounds__(256) void k_gather(const unsigned short* __restrict__ h,
                                                const int* __restrict__ row_ptr,
                                                const int2* __restrict__ csr,
                                                const float* __restrict__ dinv,
                                                const float* __restrict__ b,
                                                float* __restrict__ out, int N) {
    constexpr int LPN = C / 4;
    const int tid  = blockIdx.x * blockDim.x + threadIdx.x;
    const int node = tid / LPN;
    const int lane = tid % LPN;
    if (node >= N) return;

    const float dn = dinv[node];
    float4 acc = reinterpret_cast<const float4*>(b)[lane];
    {
        const float w = dn * dn;  // self loop
        const ushort4 v = *reinterpret_cast<const ushort4*>(h + (size_t)node * C + lane * 4);
        acc.x = fmaf(bf2f(v.x), w, acc.x); acc.y = fmaf(bf2f(v.y), w, acc.y);
        acc.z = fmaf(bf2f(v.z), w, acc.z); acc.w = fmaf(bf2f(v.w), w, acc.w);
    }

    const int e1 = row_ptr[node + 1];
    int e = row_ptr[node];
    for (; e + 1 < e1; e += 2) {
        const int2 r0 = csr[e];
        const int2 r1 = csr[e + 1];
        const float w0 = __int_as_float(r0.y) * dn;
        const float w1 = __int_as_float(r1.y) * dn;
        const ushort4 v0 = *reinterpret_cast<const ushort4*>(h + (size_t)r0.x * C + lane * 4);
        const ushort4 v1 = *reinterpret_cast<const ushort4*>(h + (size_t)r1.x * C + lane * 4);
        acc.x = fmaf(bf2f(v0.x), w0, acc.x); acc.y = fmaf(bf2f(v0.y), w0, acc.y);
        acc.z = fmaf(bf2f(v0.z), w0, acc.z); acc.w = fmaf(bf2f(v0.w), w0, acc.w);
        acc.x = fmaf(bf2f(v1.x), w1, acc.x); acc.y = fmaf(bf2f(v1.y), w1, acc.y);
        acc.z = fmaf(bf2f(v1.z), w1, acc.z); acc.w = fmaf(bf2f(v1.w), w1, acc.w);
    }
    if (e < e1) {
        const int2 r0 = csr[e];
        const float w0 = __int_as_float(r0.y) * dn;
        const ushort4 v0 = *reinterpret_cast<const ushort4*>(h + (size_t)r0.x * C + lane * 4);
        acc.x = fmaf(bf2f(v0.x), w0, acc.x); acc.y = fmaf(bf2f(v0.y), w0, acc.y);
        acc.z = fmaf(bf2f(v0.z), w0, acc.z); acc.w = fmaf(bf2f(v0.w), w0, acc.w);
    }

    reinterpret_cast<float4*>(out + (size_t)node * C)[lane] = acc;
}

extern "C" void kernel_launch(void* const* d_in, const int* in_sizes, int n_in,
                              void* d_out, int out_size, void* d_ws, size_t ws_size,
                              hipStream_t stream) {
    const float* x  = (const float*)d_in[0];
    const int*   ei = (const int*)d_in[1];
    const float* W1 = (const float*)d_in[2];
    const float* b1 = (const float*)d_in[3];
    const float* W2 = (const float*)d_in[4];
    const float* b2 = (const float*)d_in[5];
    float* out = (float*)d_out;

    const int N = in_sizes[0] / IN_CH;   // 50000
    const int E = in_sizes[1] / 2;       // 600000
    const int NBLK = (N + SCAN_CHUNK - 1) / SCAN_CHUNK;   // 13

    char* wsb = (char*)d_ws;
    size_t off = 0;
    auto alloc = [&](size_t bytes) -> void* {
        void* p = wsb + off;
        off += (bytes + 255) & ~(size_t)255;
        return p;
    };
    int*   indeg    = (int*)alloc((size_t)N * sizeof(int));
    int*   partials = (int*)alloc(64 * sizeof(int));
    float* dinv     = (float*)alloc((size_t)N * sizeof(float));
    int*   row_ptr  = (int*)alloc(((size_t)N + 1) * sizeof(int));
    int2*  csr      = (int2*)alloc((size_t)E * sizeof(int2));
    unsigned short* h1b  = (unsigned short*)alloc((size_t)N * HID * sizeof(unsigned short));
    unsigned short* aggb = (unsigned short*)alloc((size_t)N * HID * sizeof(unsigned short));
    unsigned short* h2b  = (unsigned short*)alloc((size_t)N * OUT_CH * sizeof(unsigned short));
    int*   cursor   = indeg;   // indeg dead after k_scan1

    auto gs = [](long long n) { return (int)((n + 255) / 256); };

    k_init<<<64, 256, 0, stream>>>(indeg, N);
    k_count<<<gs((E + 3) / 4), 256, 0, stream>>>(ei, indeg, E);
    k_scan1<<<NBLK, 256, 0, stream>>>(indeg, row_ptr, dinv, partials, N);
    k_scan3<<<NBLK, 256, 0, stream>>>(partials, row_ptr, cursor, N, NBLK);

    // layer 1 transform fused with CSR fill (independent work)
    const int gemmBlocks = (N + 63) / 64;        // 782
    const int fillBlocks = 1024;
    k_gemm_fill<<<gemmBlocks + fillBlocks, 256, 0, stream>>>(
        x, W1, h1b, N, gemmBlocks, ei, dinv, cursor, csr, E);

    // gather1 + bias + ReLU -> bf16 agg
    k_gather_relu<<<gs((long long)N * (HID / 4)), 256, 0, stream>>>(
        h1b, row_ptr, csr, dinv, b1, aggb, N);

    // layer 2 transform (bf16 in, bf16 out)
    k_gemm2<<<(N + 127) / 128, 256, 0, stream>>>(aggb, W2, h2b, N);

    // final gather + bias -> out (f32)
    k_gather<OUT_CH><<<gs((long long)N * (OUT_CH / 4)), 256, 0, stream>>>(
        h2b, row_ptr, csr, dinv, b2, out, N);
}